// Round 1
// baseline (6880.431 us; speedup 1.0000x reference)
//
#include <hip/hip_runtime.h>
#include <math.h>

// Problem constants (match reference)
#define S     512
#define Bsz   8
#define NCELL (S*S)              // 262144 = 2^18
#define NTOT  (Bsz*NCELL)        // 2097152
#define NFACE ((S-1)*S)          // 261632
#define NFTOT (Bsz*NFACE)        // 2093056
#define CG_ITERS 20

// h = 1/511 as the reference computes it (python double -> f32 at use sites).
__device__ __constant__ float kINVH  = 511.0f;     // multiply instead of /h (1e-8 rel diff, irrelevant)
__device__ __constant__ float kINV2H = 255.5f;     // 1/(2h)
// h*h in double, rounded to f32 (matches reference's python h*h)
__device__ __constant__ float kH2    = (float)((1.0/511.0)*(1.0/511.0));

// ---------------- geometry (replicates numpy grid_helpers bit-exactly in double) ----
__device__ __forceinline__ void geom(int i, int j, float& rhob, float& bnx, float& bny) {
    // np.linspace(0,1,S): coords[k] = k*(1/511) for k<511, coords[511] = 1.0 exactly
    double gx = (i == S-1) ? 1.0 : (double)i * (1.0/511.0);
    double gy = (j == S-1) ? 1.0 : (double)j * (1.0/511.0);
    double v0 = gx, v1 = 1.0 - gx, v2 = gy, v3 = 1.0 - gy;
    double m = v0; int am = 0;
    if (v1 < m) { m = v1; am = 1; }   // strict '<' == np.argmin first-min-wins
    if (v2 < m) { m = v2; am = 2; }
    if (v3 < m) { m = v3; am = 3; }
    float d = (float)m;               // f32 cast as in grid_helpers
    rhob = expf(-(d*d) / 0.0225f);    // DELTA*DELTA
    bnx = (am == 0) ? -1.f : (am == 1) ? 1.f : 0.f;
    bny = (am == 2) ? -1.f : (am == 3) ? 1.f : 0.f;
}

// ---------------- block reduction (256 threads -> thread 0), double precision ------
__device__ __forceinline__ double blockReduce256(double v, double* lds) {
    for (int off = 32; off > 0; off >>= 1) v += __shfl_down(v, off, 64);
    int lane = threadIdx.x & 63, wave = threadIdx.x >> 6;
    if (lane == 0) lds[wave] = v;
    __syncthreads();
    double s = 0.0;
    if (threadIdx.x == 0) { s = lds[0] + lds[1] + lds[2] + lds[3]; }
    return s;
}

// ================= K1: per-cell fields: lap, rho_int, sx, sy; zero scalars =========
__global__ void k_cellfields(const float* __restrict__ coeff, const float* __restrict__ u,
                             const float* __restrict__ beta,
                             float* __restrict__ lap, float* __restrict__ rho,
                             float* __restrict__ sx, float* __restrict__ sy,
                             double* __restrict__ scal) {
    int idx = blockIdx.x * 256 + threadIdx.x;
    if (idx == 0) { for (int t = 0; t < 32; ++t) scal[t] = 0.0; }
    int rem = idx & (NCELL - 1);
    int i = rem >> 9, j = rem & (S - 1);
    const float* c  = coeff + (idx - rem);
    const float* uu = u     + (idx - rem);
    float cc = c[rem];

    // lap = div(fdx(u), fdy(u)): zero on boundary cells, 5-point interior
    float lapv = 0.f;
    if (i > 0 && i < S-1 && j > 0 && j < S-1) {
        float uc = uu[rem];
        float un = uu[rem + S], us = uu[rem - S];
        float ue = uu[rem + 1], uw = uu[rem - 1];
        lapv = ((un - uc)*kINVH - (uc - us)*kINVH)*kINVH
             + ((ue - uc)*kINVH - (uc - uw)*kINVH)*kINVH;
    }
    lap[idx] = lapv;

    // centered gradient of log(max(coeff,EPS)), one-sided at edges
    float glx, gly;
    {
        float lc = logf(fmaxf(cc, 1e-6f));
        if (i == 0)        { glx = (logf(fmaxf(c[rem+S],1e-6f)) - lc) * kINVH; }
        else if (i == S-1) { glx = (lc - logf(fmaxf(c[rem-S],1e-6f))) * kINVH; }
        else { glx = (logf(fmaxf(c[rem+S],1e-6f)) - logf(fmaxf(c[rem-S],1e-6f))) * kINV2H; }
        if (j == 0)        { gly = (logf(fmaxf(c[rem+1],1e-6f)) - lc) * kINVH; }
        else if (j == S-1) { gly = (lc - logf(fmaxf(c[rem-1],1e-6f))) * kINVH; }
        else { gly = (logf(fmaxf(c[rem+1],1e-6f)) - logf(fmaxf(c[rem-1],1e-6f))) * kINV2H; }
    }
    float eta  = sqrtf(glx*glx + gly*gly + 1e-6f);
    float rhov = 1.f / (1.f + expf(-10.f * (eta - 0.5f)));  // sigmoid(GAMMA*(eta-THRESH))
    float nhx = glx / eta, nhy = gly / eta;

    float4 b4 = ((const float4*)beta)[idx];      // [bulk, n, t, b]
    rho[idx] = rhov;
    sx[idx]  = b4.y * nhx - b4.z * nhy;
    sy[idx]  = b4.y * nhy + b4.z * nhx;
}

// ================= K2x: x-face taus + cx ===========================================
__global__ void k_facex(const float* __restrict__ coeff, const float* __restrict__ u,
                        const float* __restrict__ beta,
                        const float* __restrict__ lap, const float* __restrict__ rho,
                        const float* __restrict__ sx,
                        float* __restrict__ taux, float* __restrict__ cxA) {
    int idx = blockIdx.x * 256 + threadIdx.x;         // over B*(S-1)*S, exact grid
    int b = idx / NFACE;
    int rem = idx - b * NFACE;
    int fi = rem >> 9, j = rem & (S - 1);
    int cell0 = b * NCELL + fi * S + j;
    int cell1 = cell0 + S;

    float c0 = coeff[cell0], c1 = coeff[cell1];
    float cx = 2.f * c1 * c0 / (c1 + c0 + 1e-6f);
    cxA[idx] = cx;

    float t = 0.f;
    if (j > 0 && j < S-1) {                            // xmask
        float gux = (u[cell1]   - u[cell0])   * kINVH;
        float lgx = (lap[cell1] - lap[cell0]) * kINVH;
        float4 b0 = ((const float4*)beta)[cell0];
        float4 b1 = ((const float4*)beta)[cell1];
        float rb0, nx0, ny0, rb1, nx1, ny1;
        geom(fi,   j, rb0, nx0, ny0);
        geom(fi+1, j, rb1, nx1, ny1);
        float abb  = 0.5f * (b1.x + b0.x);
        float arho = 0.5f * (rho[cell1] + rho[cell0]);
        float asx  = 0.5f * (sx[cell1]  + sx[cell0]);
        float arb  = 0.5f * (rb1 + rb0);
        float abx  = 0.5f * (b1.w * nx1 + b0.w * nx0);
        t = abb * kH2 * cx * lgx + arho * asx * cx * gux + arb * abx * cx * gux;
    }
    taux[idx] = t;
}

// ================= K2y: y-face taus + cy ===========================================
__global__ void k_facey(const float* __restrict__ coeff, const float* __restrict__ u,
                        const float* __restrict__ beta,
                        const float* __restrict__ lap, const float* __restrict__ rho,
                        const float* __restrict__ sy,
                        float* __restrict__ tauy, float* __restrict__ cyA) {
    int idx = blockIdx.x * 256 + threadIdx.x;         // over B*S*(S-1)
    int b = idx / NFACE;
    int rem = idx - b * NFACE;
    int i = rem / (S - 1);
    int fj = rem - i * (S - 1);
    int cell0 = b * NCELL + i * S + fj;
    int cell1 = cell0 + 1;

    float c0 = coeff[cell0], c1 = coeff[cell1];
    float cy = 2.f * c1 * c0 / (c1 + c0 + 1e-6f);
    cyA[idx] = cy;

    float t = 0.f;
    if (i > 0 && i < S-1) {                            // ymask
        float guy = (u[cell1]   - u[cell0])   * kINVH;
        float lgy = (lap[cell1] - lap[cell0]) * kINVH;
        float4 b0 = ((const float4*)beta)[cell0];
        float4 b1 = ((const float4*)beta)[cell1];
        float rb0, nx0, ny0, rb1, nx1, ny1;
        geom(i, fj,   rb0, nx0, ny0);
        geom(i, fj+1, rb1, nx1, ny1);
        float abb  = 0.5f * (b1.x + b0.x);
        float arho = 0.5f * (rho[cell1] + rho[cell0]);
        float asy  = 0.5f * (sy[cell1]  + sy[cell0]);
        float arb  = 0.5f * (rb1 + rb0);
        float aby  = 0.5f * (b1.w * ny1 + b0.w * ny0);
        t = abb * kH2 * cy * lgy + arho * asy * cy * guy + arb * aby * cy * guy;
    }
    tauy[idx] = t;
}

// ================= K3: rhs = div(tau); r=p=rhs; x=0; rn = <r,r> ====================
__global__ void k_rhs(const float* __restrict__ taux, const float* __restrict__ tauy,
                      float* __restrict__ r, float* __restrict__ p, float* __restrict__ x,
                      double* __restrict__ rn) {
    __shared__ double lds[4];
    int idx = blockIdx.x * 256 + threadIdx.x;
    int b = idx >> 18;
    int rem = idx & (NCELL - 1);
    int i = rem >> 9, j = rem & (S - 1);
    float v = 0.f;
    if (i > 0 && i < S-1 && j > 0 && j < S-1) {
        const float* tx = taux + b * NFACE;
        const float* ty = tauy + b * NFACE;
        v = (tx[i*S + j] - tx[(i-1)*S + j]) * kINVH
          + (ty[i*(S-1) + j] - ty[i*(S-1) + j - 1]) * kINVH;
    }
    r[idx] = v; p[idx] = v; x[idx] = 0.f;
    double s = blockReduce256((double)v * (double)v, lds);
    if (threadIdx.x == 0) atomicAdd(&rn[b], s);
}

// ================= KA: ap = A(p); pap += <p,ap>; zero nn ===========================
__global__ void k_apply(const float* __restrict__ p, const float* __restrict__ cx,
                        const float* __restrict__ cy, float* __restrict__ ap,
                        double* __restrict__ pap, double* __restrict__ nn) {
    __shared__ double lds[4];
    int idx = blockIdx.x * 256 + threadIdx.x;
    int b = idx >> 18;
    int rem = idx & (NCELL - 1);
    int i = rem >> 9, j = rem & (S - 1);
    if (rem == 0) nn[b] = 0.0;                 // reset for KB's accumulation
    float pc = p[idx];
    float apv;
    if (i > 0 && i < S-1 && j > 0 && j < S-1) {
        const float* cxb = cx + b * NFACE;
        const float* cyb = cy + b * NFACE;
        float pn = p[idx + S], ps = p[idx - S];
        float pe = p[idx + 1], pw = p[idx - 1];
        float qxp = cxb[i*S + j]       * ((pn - pc) * kINVH);
        float qxm = cxb[(i-1)*S + j]   * ((pc - ps) * kINVH);
        float qyp = cyb[i*(S-1) + j]   * ((pe - pc) * kINVH);
        float qym = cyb[i*(S-1) + j-1] * ((pc - pw) * kINVH);
        apv = -((qxp - qxm) * kINVH + (qyp - qym) * kINVH);
    } else {
        apv = pc;                               // Dirichlet rows: A(p)=p (p==0 there)
    }
    ap[idx] = apv;
    double s = blockReduce256((double)pc * (double)apv, lds);
    if (threadIdx.x == 0) atomicAdd(&pap[b], s);
}

// ================= KB: alpha; x += a*p; r -= a*ap; nn += <r,r> =====================
__global__ void k_update_xr(const float* __restrict__ p, const float* __restrict__ ap,
                            float* __restrict__ x, float* __restrict__ r,
                            const double* __restrict__ rn, const double* __restrict__ pap,
                            double* __restrict__ nn) {
    __shared__ double lds[4];
    int idx = blockIdx.x * 256 + threadIdx.x;
    int b = idx >> 18;
    float alpha = (float)(rn[b] / fmax(pap[b], 1e-6));
    float rv = r[idx] - alpha * ap[idx];
    x[idx] = x[idx] + alpha * p[idx];   // boundary: p==0 -> x stays 0 (zb implicit)
    r[idx] = rv;
    double s = blockReduce256((double)rv * (double)rv, lds);
    if (threadIdx.x == 0) atomicAdd(&nn[b], s);
}

// ================= KC: beta; p = r + beta*p; rn_next = nn; pap = 0 =================
__global__ void k_update_p(const float* __restrict__ r, float* __restrict__ p,
                           const double* __restrict__ rn, const double* __restrict__ nn,
                           double* __restrict__ rn_next, double* __restrict__ pap) {
    int idx = blockIdx.x * 256 + threadIdx.x;
    int b = idx >> 18;
    int rem = idx & (NCELL - 1);
    float beta = (float)(nn[b] / fmax(rn[b], 1e-6));
    p[idx] = r[idx] + beta * p[idx];
    if (rem == 0) { rn_next[b] = nn[b]; pap[b] = 0.0; }
}

// ================= KF: out = zb(u + x), in place (x lives in d_out) ================
__global__ void k_final(const float* __restrict__ u, float* __restrict__ out) {
    int idx = blockIdx.x * 256 + threadIdx.x;
    int rem = idx & (NCELL - 1);
    int i = rem >> 9, j = rem & (S - 1);
    float v = 0.f;
    if (i > 0 && i < S-1 && j > 0 && j < S-1) v = u[idx] + out[idx];
    out[idx] = v;
}

extern "C" void kernel_launch(void* const* d_in, const int* in_sizes, int n_in,
                              void* d_out, int out_size, void* d_ws, size_t ws_size,
                              hipStream_t stream) {
    const float* coeff = (const float*)d_in[0];
    const float* u     = (const float*)d_in[1];
    const float* beta  = (const float*)d_in[2];
    float* x = (float*)d_out;   // CG solution accumulates directly in d_out

    // workspace layout: 32 doubles of scalars, then 4 cell arrays + 4 face arrays.
    // Cell arrays double as setup temps: r<-lap, p<-rho, ap<-sx, spare<-sy.
    double* scal = (double*)d_ws;
    float* fbase = (float*)((char*)d_ws + 256);
    float* r     = fbase;
    float* p     = r  + NTOT;
    float* ap    = p  + NTOT;
    float* spare = ap + NTOT;     // sy during setup
    float* taux  = spare + NTOT;
    float* tauy  = taux + NFTOT;
    float* cxA   = tauy + NFTOT;
    float* cyA   = cxA  + NFTOT;

    double* rnA = scal + 0;   // B=8 entries each
    double* rnB = scal + 8;
    double* pap = scal + 16;
    double* nn  = scal + 24;

    dim3 blk(256);
    dim3 gridCell(NTOT / 256);    // 8192, exact
    dim3 gridFace(NFTOT / 256);   // 8176, exact

    // setup (temps alias CG arrays; all stream-ordered)
    k_cellfields<<<gridCell, blk, 0, stream>>>(coeff, u, beta, r, p, ap, spare, scal);
    k_facex<<<gridFace, blk, 0, stream>>>(coeff, u, beta, r, p, ap, taux, cxA);
    k_facey<<<gridFace, blk, 0, stream>>>(coeff, u, beta, r, p, spare, tauy, cyA);
    k_rhs<<<gridCell, blk, 0, stream>>>(taux, tauy, r, p, x, rnA);

    // CG, fixed 20 iterations, rn ping-pong to avoid scalar read/write races
    double* rcur = rnA;
    double* rnext = rnB;
    for (int it = 0; it < CG_ITERS; ++it) {
        k_apply<<<gridCell, blk, 0, stream>>>(p, cxA, cyA, ap, pap, nn);
        k_update_xr<<<gridCell, blk, 0, stream>>>(p, ap, x, r, rcur, pap, nn);
        k_update_p<<<gridCell, blk, 0, stream>>>(r, p, rcur, nn, rnext, pap);
        double* t = rcur; rcur = rnext; rnext = t;
    }

    k_final<<<gridCell, blk, 0, stream>>>(u, x);
}

// Round 2
// 997.444 us; speedup vs baseline: 6.8981x; 6.8981x over previous
//
#include <hip/hip_runtime.h>
#include <math.h>

// Problem constants (match reference)
#define S     512
#define Bsz   8
#define NCELL (S*S)              // 262144 = 2^18
#define NTOT  (Bsz*NCELL)        // 2097152
#define NFACE ((S-1)*S)          // 261632
#define NFTOT (Bsz*NFACE)        // 2093056
#define CG_ITERS 20
#define PB    1024               // partial-sum slots per batch (= blocks per batch)

__device__ __constant__ float kINVH  = 511.0f;     // 1/h
__device__ __constant__ float kINV2H = 255.5f;     // 1/(2h)
__device__ __constant__ float kH2    = (float)((1.0/511.0)*(1.0/511.0));

// ---------------- geometry (replicates numpy grid_helpers bit-exactly in double) ----
__device__ __forceinline__ void geom(int i, int j, float& rhob, float& bnx, float& bny) {
    double gx = (i == S-1) ? 1.0 : (double)i * (1.0/511.0);
    double gy = (j == S-1) ? 1.0 : (double)j * (1.0/511.0);
    double v0 = gx, v1 = 1.0 - gx, v2 = gy, v3 = 1.0 - gy;
    double m = v0; int am = 0;
    if (v1 < m) { m = v1; am = 1; }   // strict '<' == np.argmin first-min-wins
    if (v2 < m) { m = v2; am = 2; }
    if (v3 < m) { m = v3; am = 3; }
    float d = (float)m;
    rhob = expf(-(d*d) / 0.0225f);
    bnx = (am == 0) ? -1.f : (am == 1) ? 1.f : 0.f;
    bny = (am == 2) ? -1.f : (am == 3) ? 1.f : 0.f;
}

// ---- block reduce 256 threads -> single double (valid in thread 0 only) -----------
__device__ __forceinline__ double blockSum(double v, double* lds) {
    for (int off = 32; off > 0; off >>= 1) v += __shfl_down(v, off, 64);
    int lane = threadIdx.x & 63, wave = threadIdx.x >> 6;
    if (lane == 0) lds[wave] = v;
    __syncthreads();
    return lds[0] + lds[1] + lds[2] + lds[3];   // correct in every thread
}

// ---- reduce 1024 per-batch partials -> scalar, result valid in ALL threads --------
__device__ __forceinline__ double reducePartials(const double* __restrict__ part, double* lds) {
    int t = threadIdx.x;
    double v = part[t] + part[t + 256] + part[t + 512] + part[t + 768];
    for (int off = 32; off > 0; off >>= 1) v += __shfl_down(v, off, 64);
    int lane = t & 63, wave = t >> 6;
    if (lane == 0) lds[wave] = v;
    __syncthreads();
    double s = lds[0] + lds[1] + lds[2] + lds[3];
    __syncthreads();                 // lds reusable by caller afterwards
    return s;
}

// ================= K1: per-cell fields: lap, rho_int, sx, sy =======================
__global__ void k_cellfields(const float* __restrict__ coeff, const float* __restrict__ u,
                             const float* __restrict__ beta,
                             float* __restrict__ lap, float* __restrict__ rho,
                             float* __restrict__ sx, float* __restrict__ sy) {
    int idx = blockIdx.x * 256 + threadIdx.x;
    int rem = idx & (NCELL - 1);
    int i = rem >> 9, j = rem & (S - 1);
    const float* c  = coeff + (idx - rem);
    const float* uu = u     + (idx - rem);
    float cc = c[rem];

    float lapv = 0.f;
    if (i > 0 && i < S-1 && j > 0 && j < S-1) {
        float uc = uu[rem];
        float un = uu[rem + S], us = uu[rem - S];
        float ue = uu[rem + 1], uw = uu[rem - 1];
        lapv = ((un - uc)*kINVH - (uc - us)*kINVH)*kINVH
             + ((ue - uc)*kINVH - (uc - uw)*kINVH)*kINVH;
    }
    lap[idx] = lapv;

    float glx, gly;
    {
        float lc = logf(fmaxf(cc, 1e-6f));
        if (i == 0)        { glx = (logf(fmaxf(c[rem+S],1e-6f)) - lc) * kINVH; }
        else if (i == S-1) { glx = (lc - logf(fmaxf(c[rem-S],1e-6f))) * kINVH; }
        else { glx = (logf(fmaxf(c[rem+S],1e-6f)) - logf(fmaxf(c[rem-S],1e-6f))) * kINV2H; }
        if (j == 0)        { gly = (logf(fmaxf(c[rem+1],1e-6f)) - lc) * kINVH; }
        else if (j == S-1) { gly = (lc - logf(fmaxf(c[rem-1],1e-6f))) * kINVH; }
        else { gly = (logf(fmaxf(c[rem+1],1e-6f)) - logf(fmaxf(c[rem-1],1e-6f))) * kINV2H; }
    }
    float eta  = sqrtf(glx*glx + gly*gly + 1e-6f);
    float rhov = 1.f / (1.f + expf(-10.f * (eta - 0.5f)));
    float nhx = glx / eta, nhy = gly / eta;

    float4 b4 = ((const float4*)beta)[idx];
    rho[idx] = rhov;
    sx[idx]  = b4.y * nhx - b4.z * nhy;
    sy[idx]  = b4.y * nhy + b4.z * nhx;
}

// ================= K2x: x-face taus + cx ===========================================
__global__ void k_facex(const float* __restrict__ coeff, const float* __restrict__ u,
                        const float* __restrict__ beta,
                        const float* __restrict__ lap, const float* __restrict__ rho,
                        const float* __restrict__ sx,
                        float* __restrict__ taux, float* __restrict__ cxA) {
    int idx = blockIdx.x * 256 + threadIdx.x;
    int b = idx / NFACE;
    int rem = idx - b * NFACE;
    int fi = rem >> 9, j = rem & (S - 1);
    int cell0 = b * NCELL + fi * S + j;
    int cell1 = cell0 + S;

    float c0 = coeff[cell0], c1 = coeff[cell1];
    float cx = 2.f * c1 * c0 / (c1 + c0 + 1e-6f);
    cxA[idx] = cx;

    float t = 0.f;
    if (j > 0 && j < S-1) {
        float gux = (u[cell1]   - u[cell0])   * kINVH;
        float lgx = (lap[cell1] - lap[cell0]) * kINVH;
        float4 b0 = ((const float4*)beta)[cell0];
        float4 b1 = ((const float4*)beta)[cell1];
        float rb0, nx0, ny0, rb1, nx1, ny1;
        geom(fi,   j, rb0, nx0, ny0);
        geom(fi+1, j, rb1, nx1, ny1);
        float abb  = 0.5f * (b1.x + b0.x);
        float arho = 0.5f * (rho[cell1] + rho[cell0]);
        float asx  = 0.5f * (sx[cell1]  + sx[cell0]);
        float arb  = 0.5f * (rb1 + rb0);
        float abx  = 0.5f * (b1.w * nx1 + b0.w * nx0);
        t = abb * kH2 * cx * lgx + arho * asx * cx * gux + arb * abx * cx * gux;
    }
    taux[idx] = t;
}

// ================= K2y: y-face taus + cy ===========================================
__global__ void k_facey(const float* __restrict__ coeff, const float* __restrict__ u,
                        const float* __restrict__ beta,
                        const float* __restrict__ lap, const float* __restrict__ rho,
                        const float* __restrict__ sy,
                        float* __restrict__ tauy, float* __restrict__ cyA) {
    int idx = blockIdx.x * 256 + threadIdx.x;
    int b = idx / NFACE;
    int rem = idx - b * NFACE;
    int i = rem / (S - 1);
    int fj = rem - i * (S - 1);
    int cell0 = b * NCELL + i * S + fj;
    int cell1 = cell0 + 1;

    float c0 = coeff[cell0], c1 = coeff[cell1];
    float cy = 2.f * c1 * c0 / (c1 + c0 + 1e-6f);
    cyA[idx] = cy;

    float t = 0.f;
    if (i > 0 && i < S-1) {
        float guy = (u[cell1]   - u[cell0])   * kINVH;
        float lgy = (lap[cell1] - lap[cell0]) * kINVH;
        float4 b0 = ((const float4*)beta)[cell0];
        float4 b1 = ((const float4*)beta)[cell1];
        float rb0, nx0, ny0, rb1, nx1, ny1;
        geom(i, fj,   rb0, nx0, ny0);
        geom(i, fj+1, rb1, nx1, ny1);
        float abb  = 0.5f * (b1.x + b0.x);
        float arho = 0.5f * (rho[cell1] + rho[cell0]);
        float asy  = 0.5f * (sy[cell1]  + sy[cell0]);
        float arb  = 0.5f * (rb1 + rb0);
        float aby  = 0.5f * (b1.w * ny1 + b0.w * ny0);
        t = abb * kH2 * cy * lgy + arho * asy * cy * guy + arb * aby * cy * guy;
    }
    tauy[idx] = t;
}

// ================= K3: rhs = div(tau); r=p=rhs; x=0; rrPart[blk] = <r,r> part ======
__global__ void k_rhs(const float* __restrict__ taux, const float* __restrict__ tauy,
                      float* __restrict__ r, float* __restrict__ p, float* __restrict__ x,
                      double* __restrict__ rrPart) {
    __shared__ double lds[4];
    int idx = blockIdx.x * 256 + threadIdx.x;
    int b = idx >> 18;
    int rem = idx & (NCELL - 1);
    int i = rem >> 9, j = rem & (S - 1);
    float v = 0.f;
    if (i > 0 && i < S-1 && j > 0 && j < S-1) {
        const float* tx = taux + b * NFACE;
        const float* ty = tauy + b * NFACE;
        v = (tx[i*S + j] - tx[(i-1)*S + j]) * kINVH
          + (ty[i*(S-1) + j] - ty[i*(S-1) + j - 1]) * kINVH;
    }
    r[idx] = v; p[idx] = v; x[idx] = 0.f;
    double s = blockSum((double)v * (double)v, lds);
    if (threadIdx.x == 0) rrPart[blockIdx.x] = s;    // blockIdx = b*PB + blockInBatch
}

// ================= KA: ap = A(p); papPart[blk] = <p,ap> partial ====================
__global__ void k_apply(const float* __restrict__ p, const float* __restrict__ cx,
                        const float* __restrict__ cy, float* __restrict__ ap,
                        double* __restrict__ papPart) {
    __shared__ double lds[4];
    int idx = blockIdx.x * 256 + threadIdx.x;
    int b = idx >> 18;
    int rem = idx & (NCELL - 1);
    int i = rem >> 9, j = rem & (S - 1);
    float pc = p[idx];
    float apv;
    if (i > 0 && i < S-1 && j > 0 && j < S-1) {
        const float* cxb = cx + b * NFACE;
        const float* cyb = cy + b * NFACE;
        float pn = p[idx + S], ps = p[idx - S];
        float pe = p[idx + 1], pw = p[idx - 1];
        float qxp = cxb[i*S + j]       * ((pn - pc) * kINVH);
        float qxm = cxb[(i-1)*S + j]   * ((pc - ps) * kINVH);
        float qyp = cyb[i*(S-1) + j]   * ((pe - pc) * kINVH);
        float qym = cyb[i*(S-1) + j-1] * ((pc - pw) * kINVH);
        apv = -((qxp - qxm) * kINVH + (qyp - qym) * kINVH);
    } else {
        apv = pc;
    }
    ap[idx] = apv;
    double s = blockSum((double)pc * (double)apv, lds);
    if (threadIdx.x == 0) papPart[blockIdx.x] = s;
}

// ====== KB: rn=Σ rrOld, pap=Σ papPart; alpha; x+=a*p; r-=a*ap; rrNew part ==========
__global__ void k_update_xr(const float* __restrict__ p, const float* __restrict__ ap,
                            float* __restrict__ x, float* __restrict__ r,
                            const double* __restrict__ rrOld,
                            const double* __restrict__ papPart,
                            double* __restrict__ rrNew) {
    __shared__ double lds[4];
    int idx = blockIdx.x * 256 + threadIdx.x;
    int b = idx >> 18;
    double rn  = reducePartials(rrOld  + b * PB, lds);
    double pap = reducePartials(papPart + b * PB, lds);
    float alpha = (float)(rn / fmax(pap, 1e-6));
    float rv = r[idx] - alpha * ap[idx];
    x[idx] = x[idx] + alpha * p[idx];   // p==0 on boundary -> zb(x) implicit
    r[idx] = rv;
    double s = blockSum((double)rv * (double)rv, lds);
    if (threadIdx.x == 0) rrNew[blockIdx.x] = s;
}

// ====== KC: nn=Σ rrNew, rn=Σ rrOld; beta; p = r + beta*p ===========================
__global__ void k_update_p(const float* __restrict__ r, float* __restrict__ p,
                           const double* __restrict__ rrOld,
                           const double* __restrict__ rrNew) {
    __shared__ double lds[4];
    int idx = blockIdx.x * 256 + threadIdx.x;
    int b = idx >> 18;
    double nn = reducePartials(rrNew + b * PB, lds);
    double rn = reducePartials(rrOld + b * PB, lds);
    float beta = (float)(nn / fmax(rn, 1e-6));
    p[idx] = r[idx] + beta * p[idx];
}

// ================= KF: out = zb(u + x), in place (x lives in d_out) ================
__global__ void k_final(const float* __restrict__ u, float* __restrict__ out) {
    int idx = blockIdx.x * 256 + threadIdx.x;
    int rem = idx & (NCELL - 1);
    int i = rem >> 9, j = rem & (S - 1);
    float v = 0.f;
    if (i > 0 && i < S-1 && j > 0 && j < S-1) v = u[idx] + out[idx];
    out[idx] = v;
}

extern "C" void kernel_launch(void* const* d_in, const int* in_sizes, int n_in,
                              void* d_out, int out_size, void* d_ws, size_t ws_size,
                              hipStream_t stream) {
    const float* coeff = (const float*)d_in[0];
    const float* u     = (const float*)d_in[1];
    const float* beta  = (const float*)d_in[2];
    float* x = (float*)d_out;   // CG solution accumulates directly in d_out

    // workspace layout: float arrays, then per-block partial buffers (doubles).
    float* fbase = (float*)d_ws;
    float* r     = fbase;
    float* p     = r  + NTOT;
    float* ap    = p  + NTOT;
    float* spare = ap + NTOT;     // sy during setup
    float* taux  = spare + NTOT;
    float* tauy  = taux + NFTOT;
    float* cxA   = tauy + NFTOT;
    float* cyA   = cxA  + NFTOT;
    double* dbase   = (double*)(cyA + NFTOT);
    double* rrA     = dbase;              // Bsz*PB = 8192 doubles
    double* rrB     = rrA + Bsz*PB;
    double* papPart = rrB + Bsz*PB;

    dim3 blk(256);
    dim3 gridCell(NTOT / 256);    // 8192, exact; 1024 blocks per batch
    dim3 gridFace(NFTOT / 256);   // 8176, exact

    // setup (temps alias CG arrays; all stream-ordered)
    k_cellfields<<<gridCell, blk, 0, stream>>>(coeff, u, beta, r, p, ap, spare);
    k_facex<<<gridFace, blk, 0, stream>>>(coeff, u, beta, r, p, ap, taux, cxA);
    k_facey<<<gridFace, blk, 0, stream>>>(coeff, u, beta, r, p, spare, tauy, cyA);
    k_rhs<<<gridCell, blk, 0, stream>>>(taux, tauy, r, p, x, rrA);

    // CG, fixed 20 iterations; <r,r> partial buffers ping-pong
    double* rrOld = rrA;
    double* rrNew = rrB;
    for (int it = 0; it < CG_ITERS; ++it) {
        k_apply<<<gridCell, blk, 0, stream>>>(p, cxA, cyA, ap, papPart);
        k_update_xr<<<gridCell, blk, 0, stream>>>(p, ap, x, r, rrOld, papPart, rrNew);
        k_update_p<<<gridCell, blk, 0, stream>>>(r, p, rrOld, rrNew);
        double* t = rrOld; rrOld = rrNew; rrNew = t;
    }

    k_final<<<gridCell, blk, 0, stream>>>(u, x);
}

// Round 3
// 626.140 us; speedup vs baseline: 10.9886x; 1.5930x over previous
//
#include <hip/hip_runtime.h>
#include <math.h>

// Problem constants (match reference)
#define S     512
#define Bsz   8
#define NCELL (S*S)              // 262144 = 2^18
#define NTOT  (Bsz*NCELL)        // 2097152
#define NFACE ((S-1)*S)          // 261632
#define NFTOT (Bsz*NFACE)
#define CG_ITERS 20
#define PB    256                // partial slots per batch (loop kernels: 256 blocks/batch)

__device__ __constant__ float kINVH  = 511.0f;     // 1/h (same as R2 - passing numerics)
__device__ __constant__ float kINV2H = 255.5f;
__device__ __constant__ float kH2    = (float)((1.0/511.0)*(1.0/511.0));

// ---------------- geometry (replicates numpy grid_helpers bit-exactly in double) ----
__device__ __forceinline__ void geom(int i, int j, float& rhob, float& bnx, float& bny) {
    double gx = (i == S-1) ? 1.0 : (double)i * (1.0/511.0);
    double gy = (j == S-1) ? 1.0 : (double)j * (1.0/511.0);
    double v0 = gx, v1 = 1.0 - gx, v2 = gy, v3 = 1.0 - gy;
    double m = v0; int am = 0;
    if (v1 < m) { m = v1; am = 1; }   // strict '<' == np.argmin first-min-wins
    if (v2 < m) { m = v2; am = 2; }
    if (v3 < m) { m = v3; am = 3; }
    float d = (float)m;
    rhob = expf(-(d*d) / 0.0225f);
    bnx = (am == 0) ? -1.f : (am == 1) ? 1.f : 0.f;
    bny = (am == 2) ? -1.f : (am == 3) ? 1.f : 0.f;
}

// ---- block reduce 256 threads -> double, valid in all threads ---------------------
__device__ __forceinline__ double blockSum(double v, double* lds) {
    for (int off = 32; off > 0; off >>= 1) v += __shfl_down(v, off, 64);
    int lane = threadIdx.x & 63, wave = threadIdx.x >> 6;
    __syncthreads();                       // protect lds from any prior use
    if (lane == 0) lds[wave] = v;
    __syncthreads();
    return lds[0] + lds[1] + lds[2] + lds[3];
}

// ---- reduce 256 per-batch partials -> scalar, valid in all threads ----------------
__device__ __forceinline__ double reducePartials256(const double* __restrict__ part, double* lds) {
    double v = part[threadIdx.x];
    for (int off = 32; off > 0; off >>= 1) v += __shfl_down(v, off, 64);
    int lane = threadIdx.x & 63, wave = threadIdx.x >> 6;
    __syncthreads();
    if (lane == 0) lds[wave] = v;
    __syncthreads();
    return lds[0] + lds[1] + lds[2] + lds[3];
}

// ================= K1: per-cell fields: lap, rho_int, sx, sy =======================
__global__ void k_cellfields(const float* __restrict__ coeff, const float* __restrict__ u,
                             const float* __restrict__ beta,
                             float* __restrict__ lap, float* __restrict__ rho,
                             float* __restrict__ sx, float* __restrict__ sy) {
    int idx = blockIdx.x * 256 + threadIdx.x;
    int rem = idx & (NCELL - 1);
    int i = rem >> 9, j = rem & (S - 1);
    const float* c  = coeff + (idx - rem);
    const float* uu = u     + (idx - rem);
    float cc = c[rem];

    float lapv = 0.f;
    if (i > 0 && i < S-1 && j > 0 && j < S-1) {
        float uc = uu[rem];
        float un = uu[rem + S], us = uu[rem - S];
        float ue = uu[rem + 1], uw = uu[rem - 1];
        lapv = ((un - uc)*kINVH - (uc - us)*kINVH)*kINVH
             + ((ue - uc)*kINVH - (uc - uw)*kINVH)*kINVH;
    }
    lap[idx] = lapv;

    float glx, gly;
    {
        float lc = logf(fmaxf(cc, 1e-6f));
        if (i == 0)        { glx = (logf(fmaxf(c[rem+S],1e-6f)) - lc) * kINVH; }
        else if (i == S-1) { glx = (lc - logf(fmaxf(c[rem-S],1e-6f))) * kINVH; }
        else { glx = (logf(fmaxf(c[rem+S],1e-6f)) - logf(fmaxf(c[rem-S],1e-6f))) * kINV2H; }
        if (j == 0)        { gly = (logf(fmaxf(c[rem+1],1e-6f)) - lc) * kINVH; }
        else if (j == S-1) { gly = (lc - logf(fmaxf(c[rem-1],1e-6f))) * kINVH; }
        else { gly = (logf(fmaxf(c[rem+1],1e-6f)) - logf(fmaxf(c[rem-1],1e-6f))) * kINV2H; }
    }
    float eta  = sqrtf(glx*glx + gly*gly + 1e-6f);
    float rhov = 1.f / (1.f + expf(-10.f * (eta - 0.5f)));
    float nhx = glx / eta, nhy = gly / eta;

    float4 b4 = ((const float4*)beta)[idx];
    rho[idx] = rhov;
    sx[idx]  = b4.y * nhx - b4.z * nhy;
    sy[idx]  = b4.y * nhy + b4.z * nhx;
}

// ================= K2: fused x-face + y-face taus (tauy stored width-512 padded) ===
__global__ void k_faces(const float* __restrict__ coeff, const float* __restrict__ u,
                        const float* __restrict__ beta,
                        const float* __restrict__ lap, const float* __restrict__ rho,
                        const float* __restrict__ sx, const float* __restrict__ sy,
                        float* __restrict__ taux, float* __restrict__ tauyP) {
    int idx = blockIdx.x * 256 + threadIdx.x;
    int b = idx >> 18;
    int rem = idx & (NCELL - 1);
    int i = rem >> 9, j = rem & (S - 1);

    float c0 = coeff[idx];
    float u0 = u[idx];
    float lap0 = lap[idx], rho0 = rho[idx];
    float4 b0 = ((const float4*)beta)[idx];
    float rb0, nx0, ny0; geom(i, j, rb0, nx0, ny0);

    if (i < S-1) {                         // x-face (i,j): cells (i,j),(i+1,j)
        int c1i = idx + S;
        float c1 = coeff[c1i];
        float cx = 2.f * c1 * c0 / (c1 + c0 + 1e-6f);
        float t = 0.f;
        if (j > 0 && j < S-1) {
            float gux = (u[c1i]   - u0)   * kINVH;
            float lgx = (lap[c1i] - lap0) * kINVH;
            float4 b1 = ((const float4*)beta)[c1i];
            float rb1, nx1, ny1; geom(i+1, j, rb1, nx1, ny1);
            float abb  = 0.5f * (b1.x + b0.x);
            float arho = 0.5f * (rho[c1i] + rho0);
            float asx  = 0.5f * (sx[c1i]  + sx[idx]);
            float arb  = 0.5f * (rb1 + rb0);
            float abx  = 0.5f * (b1.w * nx1 + b0.w * nx0);
            t = abb * kH2 * cx * lgx + arho * asx * cx * gux + arb * abx * cx * gux;
        }
        taux[b * NFACE + i * S + j] = t;
    }
    if (j < S-1) {                         // y-face (i,j): cells (i,j),(i,j+1)
        int c1i = idx + 1;
        float c1 = coeff[c1i];
        float cy = 2.f * c1 * c0 / (c1 + c0 + 1e-6f);
        float t = 0.f;
        if (i > 0 && i < S-1) {
            float guy = (u[c1i]   - u0)   * kINVH;
            float lgy = (lap[c1i] - lap0) * kINVH;
            float4 b1 = ((const float4*)beta)[c1i];
            float rb1, nx1, ny1; geom(i, j+1, rb1, nx1, ny1);
            float abb  = 0.5f * (b1.x + b0.x);
            float arho = 0.5f * (rho[c1i] + rho0);
            float asy  = 0.5f * (sy[c1i]  + sy[idx]);
            float arb  = 0.5f * (rb1 + rb0);
            float aby  = 0.5f * (b1.w * ny1 + b0.w * ny0);
            t = abb * kH2 * cy * lgy + arho * asy * cy * guy + arb * aby * cy * guy;
        }
        tauyP[b * NCELL + i * S + j] = t;  // padded to width 512
    }
}

// ================= K3: rhs = div(tau); r=p=rhs; x=0; rr partials (PB=256) ==========
__global__ void k_rhs(const float* __restrict__ taux, const float* __restrict__ tauyP,
                      float* __restrict__ r, float* __restrict__ p, float* __restrict__ x,
                      double* __restrict__ rrPart) {
    __shared__ double lds[4];
    int t = blockIdx.x * 256 + threadIdx.x;      // float4-group index
    int b = t >> 16;
    int rem = t & 65535;
    int i = rem >> 7;
    int j0 = (rem & 127) << 2;

    float4 o = make_float4(0.f, 0.f, 0.f, 0.f);
    float* oa = (float*)&o;
    if (i > 0 && i < S-1) {
        const float* tx  = taux  + b * NFACE;
        const float* typ = tauyP + b * NCELL;
        float4 txC = ((const float4*)tx)[i * 128 + (j0 >> 2)];
        float4 txS = ((const float4*)tx)[(i-1) * 128 + (j0 >> 2)];
        float4 tyC = ((const float4*)typ)[i * 128 + (j0 >> 2)];
        float tyW = (j0 > 0) ? typ[i * S + j0 - 1] : 0.f;
        const float* txCa = (const float*)&txC;
        const float* txSa = (const float*)&txS;
        const float* tyCa = (const float*)&tyC;
        #pragma unroll
        for (int k = 0; k < 4; ++k) {
            int j = j0 + k;
            if (j > 0 && j < S-1) {
                float tyw = (k == 0) ? tyW : tyCa[k-1];
                oa[k] = (txCa[k] - txSa[k]) * kINVH + (tyCa[k] - tyw) * kINVH;
            }
        }
    }
    ((float4*)r)[t] = o;
    ((float4*)p)[t] = o;
    ((float4*)x)[t] = make_float4(0.f, 0.f, 0.f, 0.f);
    double local = (double)oa[0]*oa[0] + (double)oa[1]*oa[1]
                 + (double)oa[2]*oa[2] + (double)oa[3]*oa[3];
    double s = blockSum(local, lds);
    if (threadIdx.x == 0) rrPart[blockIdx.x] = s;
}

// ====== KA: beta; p_new = r + beta*p_old (incl. halo recompute); ap = A(p_new);
//            harmonic face coeffs recomputed from coeff; pap partials ===============
__global__ void k_papply(const float* __restrict__ coeff,
                         const float* __restrict__ r,
                         const float* __restrict__ pA,
                         float* __restrict__ pB,
                         float* __restrict__ ap,
                         const double* __restrict__ rrOld,   // rn_{k-1} partials
                         const double* __restrict__ rrNew,   // rn_k partials
                         double* __restrict__ papPart,
                         int first) {
    __shared__ double lds[4];
    int t = blockIdx.x * 256 + threadIdx.x;
    int b = t >> 16;
    int rem = t & 65535;
    int i = rem >> 7;
    int j0 = (rem & 127) << 2;
    int idx = (b << 18) + (i << 9) + j0;
    int v = idx >> 2;

    float beta = 0.f;
    if (!first) {                                  // uniform branch (kernel arg)
        double nn = reducePartials256(rrNew + (b << 8), lds);
        double rn = reducePartials256(rrOld + (b << 8), lds);
        beta = (float)(nn / fmax(rn, 1e-6));
    }

    float4 pBo = make_float4(0.f,0.f,0.f,0.f);
    float4 apo = make_float4(0.f,0.f,0.f,0.f);
    double local = 0.0;
    if (i > 0 && i < S-1) {
        const float4* r4 = (const float4*)r;
        const float4* p4 = (const float4*)pA;
        const float4* c4 = (const float4*)coeff;
        float4 rC4 = r4[v], rN4 = r4[v+128], rS4 = r4[v-128];
        float4 pC4 = p4[v], pN4 = p4[v+128], pS4 = p4[v-128];
        float4 cC4 = c4[v], cN4 = c4[v+128], cS4 = c4[v-128];
        const float* rCa = (const float*)&rC4; const float* rNa = (const float*)&rN4;
        const float* rSa = (const float*)&rS4;
        const float* pCa = (const float*)&pC4; const float* pNa = (const float*)&pN4;
        const float* pSa = (const float*)&pS4;
        const float* cCa = (const float*)&cC4; const float* cNa = (const float*)&cN4;
        const float* cSa = (const float*)&cS4;
        float rW=0.f, pW=0.f, cW=0.f, rE=0.f, pE=0.f, cE=0.f;
        if (j0 > 0)     { rW = r[idx-1]; pW = pA[idx-1]; cW = coeff[idx-1]; }
        if (j0 + 4 < S) { rE = r[idx+4]; pE = pA[idx+4]; cE = coeff[idx+4]; }

        float pnC[4], pnN[4], pnS[4];
        #pragma unroll
        for (int k = 0; k < 4; ++k) {
            pnC[k] = rCa[k] + beta * pCa[k];       // same expr as R2's k_update_p
            pnN[k] = rNa[k] + beta * pNa[k];
            pnS[k] = rSa[k] + beta * pSa[k];
        }
        float pnW = rW + beta * pW, pnE = rE + beta * pE;

        float apk[4];
        #pragma unroll
        for (int k = 0; k < 4; ++k) {
            int j = j0 + k;
            if (j > 0 && j < S-1) {
                float cc = cCa[k], cn = cNa[k], cs = cSa[k];
                float ce = (k < 3) ? cCa[k+1] : cE;
                float cw = (k > 0) ? cCa[k-1] : cW;
                float pe = (k < 3) ? pnC[k+1] : pnE;
                float pw = (k > 0) ? pnC[k-1] : pnW;
                // harmonic means, bit-identical to R2's precomputed cx/cy
                float cxN = 2.f * cn * cc / (cn + cc + 1e-6f);
                float cxS = 2.f * cc * cs / (cc + cs + 1e-6f);
                float cyE = 2.f * ce * cc / (ce + cc + 1e-6f);
                float cyW = 2.f * cc * cw / (cc + cw + 1e-6f);
                float qxp = cxN * ((pnN[k] - pnC[k]) * kINVH);
                float qxm = cxS * ((pnC[k] - pnS[k]) * kINVH);
                float qyp = cyE * ((pe - pnC[k]) * kINVH);
                float qym = cyW * ((pnC[k] - pw) * kINVH);
                apk[k] = -((qxp - qxm) * kINVH + (qyp - qym) * kINVH);
            } else {
                apk[k] = pnC[k];                   // Dirichlet (value is 0)
            }
            local += (double)pnC[k] * (double)apk[k];
        }
        pBo.x = pnC[0]; pBo.y = pnC[1]; pBo.z = pnC[2]; pBo.w = pnC[3];
        apo.x = apk[0]; apo.y = apk[1]; apo.z = apk[2]; apo.w = apk[3];
    }
    ((float4*)pB)[v] = pBo;
    ((float4*)ap)[v] = apo;
    double s = blockSum(local, lds);
    if (threadIdx.x == 0) papPart[blockIdx.x] = s;
}

// ====== KB: alpha; x += a*p; r -= a*ap; rr partials for next iter ==================
__global__ void k_update(const float* __restrict__ pB, const float* __restrict__ ap,
                         float* __restrict__ x, float* __restrict__ r,
                         const double* __restrict__ rrNew, const double* __restrict__ papPart,
                         double* __restrict__ rrOut) {
    __shared__ double lds[4];
    int t = blockIdx.x * 256 + threadIdx.x;
    int b = t >> 16;
    double rn  = reducePartials256(rrNew  + (b << 8), lds);
    double pap = reducePartials256(papPart + (b << 8), lds);
    float alpha = (float)(rn / fmax(pap, 1e-6));
    float4 p4 = ((const float4*)pB)[t];
    float4 a4 = ((const float4*)ap)[t];
    float4 x4 = ((const float4*)x)[t];
    float4 r4 = ((const float4*)r)[t];
    x4.x = x4.x + alpha * p4.x;  r4.x = r4.x - alpha * a4.x;
    x4.y = x4.y + alpha * p4.y;  r4.y = r4.y - alpha * a4.y;
    x4.z = x4.z + alpha * p4.z;  r4.z = r4.z - alpha * a4.z;
    x4.w = x4.w + alpha * p4.w;  r4.w = r4.w - alpha * a4.w;
    ((float4*)x)[t] = x4;
    ((float4*)r)[t] = r4;
    double local = (double)r4.x*r4.x + (double)r4.y*r4.y
                 + (double)r4.z*r4.z + (double)r4.w*r4.w;
    double s = blockSum(local, lds);
    if (threadIdx.x == 0) rrOut[blockIdx.x] = s;
}

// ================= KF: out = zb(u + x), in place (x lives in d_out) ================
__global__ void k_final(const float* __restrict__ u, float* __restrict__ out) {
    int t = blockIdx.x * 256 + threadIdx.x;
    int rem = t & 65535;
    int i = rem >> 7;
    int j0 = (rem & 127) << 2;
    float4 o = make_float4(0.f, 0.f, 0.f, 0.f);
    if (i > 0 && i < S-1) {
        float4 u4 = ((const float4*)u)[t];
        float4 x4 = ((const float4*)out)[t];
        const float* ua = (const float*)&u4;
        const float* xa = (const float*)&x4;
        float* oa = (float*)&o;
        #pragma unroll
        for (int k = 0; k < 4; ++k) {
            int j = j0 + k;
            if (j > 0 && j < S-1) oa[k] = ua[k] + xa[k];
        }
    }
    ((float4*)out)[t] = o;
}

extern "C" void kernel_launch(void* const* d_in, const int* in_sizes, int n_in,
                              void* d_out, int out_size, void* d_ws, size_t ws_size,
                              hipStream_t stream) {
    const float* coeff = (const float*)d_in[0];
    const float* u     = (const float*)d_in[1];
    const float* beta  = (const float*)d_in[2];
    float* x = (float*)d_out;

    // workspace: r, pA, pB, ap (cell arrays; double as lap/rho/sx/sy during setup),
    // taux (NFTOT), tauyP (padded NTOT), then double partial buffers.
    float* fb   = (float*)d_ws;
    float* r    = fb;
    float* pA   = r    + NTOT;
    float* pB   = pA   + NTOT;
    float* ap   = pB   + NTOT;
    float* taux = ap   + NTOT;
    float* tauyP= taux + NFTOT;
    double* rrA = (double*)(tauyP + NTOT);
    double* rrB = rrA + Bsz * PB;
    double* pap = rrB + Bsz * PB;

    dim3 blk(256);

    // setup: lap->r, rho->pA, sx->pB, sy->ap (freed before the loop overwrites them)
    k_cellfields<<<8192, blk, 0, stream>>>(coeff, u, beta, r, pA, pB, ap);
    k_faces<<<8192, blk, 0, stream>>>(coeff, u, beta, r, pA, pB, ap, taux, tauyP);
    k_rhs<<<2048, blk, 0, stream>>>(taux, tauyP, r, pA, x, rrB);   // rn_0 -> rrB

    double* rrOld = rrA;   // rn_{k-1}
    double* rrNew = rrB;   // rn_k
    float* pin = pA;
    float* pout = pB;
    for (int it = 0; it < CG_ITERS; ++it) {
        k_papply<<<2048, blk, 0, stream>>>(coeff, r, pin, pout, ap, rrOld, rrNew, pap, it == 0);
        k_update<<<2048, blk, 0, stream>>>(pout, ap, x, r, rrNew, pap, rrOld);
        { double* td = rrOld; rrOld = rrNew; rrNew = td; }
        { float*  tf = pin;  pin  = pout;  pout  = tf; }
    }

    k_final<<<2048, blk, 0, stream>>>(u, x);
}

// Round 4
// 596.382 us; speedup vs baseline: 11.5370x; 1.0499x over previous
//
#include <hip/hip_runtime.h>
#include <math.h>

// Problem constants (match reference)
#define S     512
#define Bsz   8
#define NCELL (S*S)              // 262144 = 2^18
#define NTOT  (Bsz*NCELL)        // 2097152
#define NFACE ((S-1)*S)          // 261632
#define NFTOT (Bsz*NFACE)
#define CG_ITERS 20
#define PB    256                // partial slots per batch (256 blocks/batch)
#define NBLK  2048               // loop-kernel grid

__device__ __constant__ float kINVH  = 511.0f;     // 1/h
__device__ __constant__ float kINV2H = 255.5f;
__device__ __constant__ float kH2    = (float)((1.0/511.0)*(1.0/511.0));

// ---------------- geometry (replicates numpy grid_helpers bit-exactly in double) ----
__device__ __forceinline__ void geom(int i, int j, float& rhob, float& bnx, float& bny) {
    double gx = (i == S-1) ? 1.0 : (double)i * (1.0/511.0);
    double gy = (j == S-1) ? 1.0 : (double)j * (1.0/511.0);
    double v0 = gx, v1 = 1.0 - gx, v2 = gy, v3 = 1.0 - gy;
    double m = v0; int am = 0;
    if (v1 < m) { m = v1; am = 1; }   // strict '<' == np.argmin first-min-wins
    if (v2 < m) { m = v2; am = 2; }
    if (v3 < m) { m = v3; am = 3; }
    float d = (float)m;
    rhob = expf(-(d*d) / 0.0225f);
    bnx = (am == 0) ? -1.f : (am == 1) ? 1.f : 0.f;
    bny = (am == 2) ? -1.f : (am == 3) ? 1.f : 0.f;
}

// ---- block reduce 256 threads -> double, valid in all threads ---------------------
__device__ __forceinline__ double blockSum(double v, double* lds) {
    for (int off = 32; off > 0; off >>= 1) v += __shfl_down(v, off, 64);
    int lane = threadIdx.x & 63, wave = threadIdx.x >> 6;
    __syncthreads();
    if (lane == 0) lds[wave] = v;
    __syncthreads();
    return lds[0] + lds[1] + lds[2] + lds[3];
}

// ---- reduce 256 per-batch partials -> scalar, valid in all threads ----------------
__device__ __forceinline__ double reducePartials256(const double* __restrict__ part, double* lds) {
    double v = part[threadIdx.x];
    for (int off = 32; off > 0; off >>= 1) v += __shfl_down(v, off, 64);
    int lane = threadIdx.x & 63, wave = threadIdx.x >> 6;
    __syncthreads();
    if (lane == 0) lds[wave] = v;
    __syncthreads();
    return lds[0] + lds[1] + lds[2] + lds[3];
}

// ================= K1: per-cell fields: lap, rho_int, sx, sy =======================
__global__ void k_cellfields(const float* __restrict__ coeff, const float* __restrict__ u,
                             const float* __restrict__ beta,
                             float* __restrict__ lap, float* __restrict__ rho,
                             float* __restrict__ sx, float* __restrict__ sy) {
    int idx = blockIdx.x * 256 + threadIdx.x;
    int rem = idx & (NCELL - 1);
    int i = rem >> 9, j = rem & (S - 1);
    const float* c  = coeff + (idx - rem);
    const float* uu = u     + (idx - rem);
    float cc = c[rem];

    float lapv = 0.f;
    if (i > 0 && i < S-1 && j > 0 && j < S-1) {
        float uc = uu[rem];
        float un = uu[rem + S], us = uu[rem - S];
        float ue = uu[rem + 1], uw = uu[rem - 1];
        lapv = ((un - uc)*kINVH - (uc - us)*kINVH)*kINVH
             + ((ue - uc)*kINVH - (uc - uw)*kINVH)*kINVH;
    }
    lap[idx] = lapv;

    float glx, gly;
    {
        float lc = logf(fmaxf(cc, 1e-6f));
        if (i == 0)        { glx = (logf(fmaxf(c[rem+S],1e-6f)) - lc) * kINVH; }
        else if (i == S-1) { glx = (lc - logf(fmaxf(c[rem-S],1e-6f))) * kINVH; }
        else { glx = (logf(fmaxf(c[rem+S],1e-6f)) - logf(fmaxf(c[rem-S],1e-6f))) * kINV2H; }
        if (j == 0)        { gly = (logf(fmaxf(c[rem+1],1e-6f)) - lc) * kINVH; }
        else if (j == S-1) { gly = (lc - logf(fmaxf(c[rem-1],1e-6f))) * kINVH; }
        else { gly = (logf(fmaxf(c[rem+1],1e-6f)) - logf(fmaxf(c[rem-1],1e-6f))) * kINV2H; }
    }
    float eta  = sqrtf(glx*glx + gly*gly + 1e-6f);
    float rhov = 1.f / (1.f + expf(-10.f * (eta - 0.5f)));
    float nhx = glx / eta, nhy = gly / eta;

    float4 b4 = ((const float4*)beta)[idx];
    rho[idx] = rhov;
    sx[idx]  = b4.y * nhx - b4.z * nhy;
    sy[idx]  = b4.y * nhy + b4.z * nhx;
}

// ================= K2: fused x-face + y-face taus (tauy stored width-512 padded) ===
__global__ void k_faces(const float* __restrict__ coeff, const float* __restrict__ u,
                        const float* __restrict__ beta,
                        const float* __restrict__ lap, const float* __restrict__ rho,
                        const float* __restrict__ sx, const float* __restrict__ sy,
                        float* __restrict__ taux, float* __restrict__ tauyP) {
    int idx = blockIdx.x * 256 + threadIdx.x;
    int b = idx >> 18;
    int rem = idx & (NCELL - 1);
    int i = rem >> 9, j = rem & (S - 1);

    float c0 = coeff[idx];
    float u0 = u[idx];
    float lap0 = lap[idx], rho0 = rho[idx];
    float4 b0 = ((const float4*)beta)[idx];
    float rb0, nx0, ny0; geom(i, j, rb0, nx0, ny0);

    if (i < S-1) {
        int c1i = idx + S;
        float c1 = coeff[c1i];
        float cx = 2.f * c1 * c0 / (c1 + c0 + 1e-6f);
        float t = 0.f;
        if (j > 0 && j < S-1) {
            float gux = (u[c1i]   - u0)   * kINVH;
            float lgx = (lap[c1i] - lap0) * kINVH;
            float4 b1 = ((const float4*)beta)[c1i];
            float rb1, nx1, ny1; geom(i+1, j, rb1, nx1, ny1);
            float abb  = 0.5f * (b1.x + b0.x);
            float arho = 0.5f * (rho[c1i] + rho0);
            float asx  = 0.5f * (sx[c1i]  + sx[idx]);
            float arb  = 0.5f * (rb1 + rb0);
            float abx  = 0.5f * (b1.w * nx1 + b0.w * nx0);
            t = abb * kH2 * cx * lgx + arho * asx * cx * gux + arb * abx * cx * gux;
        }
        taux[b * NFACE + i * S + j] = t;
    }
    if (j < S-1) {
        int c1i = idx + 1;
        float c1 = coeff[c1i];
        float cy = 2.f * c1 * c0 / (c1 + c0 + 1e-6f);
        float t = 0.f;
        if (i > 0 && i < S-1) {
            float guy = (u[c1i]   - u0)   * kINVH;
            float lgy = (lap[c1i] - lap0) * kINVH;
            float4 b1 = ((const float4*)beta)[c1i];
            float rb1, nx1, ny1; geom(i, j+1, rb1, nx1, ny1);
            float abb  = 0.5f * (b1.x + b0.x);
            float arho = 0.5f * (rho[c1i] + rho0);
            float asy  = 0.5f * (sy[c1i]  + sy[idx]);
            float arb  = 0.5f * (rb1 + rb0);
            float aby  = 0.5f * (b1.w * ny1 + b0.w * ny0);
            t = abb * kH2 * cy * lgy + arho * asy * cy * guy + arb * aby * cy * guy;
        }
        tauyP[b * NCELL + i * S + j] = t;
    }
}

// ================= K3: rhs = div(tau); r=p=rhs; x=0; rr partials ===================
__global__ void k_rhs(const float* __restrict__ taux, const float* __restrict__ tauyP,
                      float* __restrict__ r, float* __restrict__ p, float* __restrict__ x,
                      double* __restrict__ rrPart) {
    __shared__ double lds[4];
    int t = blockIdx.x * 256 + threadIdx.x;
    int b = t >> 16;
    int rem = t & 65535;
    int i = rem >> 7;
    int j0 = (rem & 127) << 2;

    float4 o = make_float4(0.f, 0.f, 0.f, 0.f);
    float* oa = (float*)&o;
    if (i > 0 && i < S-1) {
        const float* tx  = taux  + b * NFACE;
        const float* typ = tauyP + b * NCELL;
        float4 txC = ((const float4*)tx)[i * 128 + (j0 >> 2)];
        float4 txS = ((const float4*)tx)[(i-1) * 128 + (j0 >> 2)];
        float4 tyC = ((const float4*)typ)[i * 128 + (j0 >> 2)];
        float tyW = (j0 > 0) ? typ[i * S + j0 - 1] : 0.f;
        const float* txCa = (const float*)&txC;
        const float* txSa = (const float*)&txS;
        const float* tyCa = (const float*)&tyC;
        #pragma unroll
        for (int k = 0; k < 4; ++k) {
            int j = j0 + k;
            if (j > 0 && j < S-1) {
                float tyw = (k == 0) ? tyW : tyCa[k-1];
                oa[k] = (txCa[k] - txSa[k]) * kINVH + (tyCa[k] - tyw) * kINVH;
            }
        }
    }
    ((float4*)r)[t] = o;
    ((float4*)p)[t] = o;
    ((float4*)x)[t] = make_float4(0.f, 0.f, 0.f, 0.f);
    double local = (double)oa[0]*oa[0] + (double)oa[1]*oa[1]
                 + (double)oa[2]*oa[2] + (double)oa[3]*oa[3];
    double s = blockSum(local, lds);
    if (threadIdx.x == 0) rrPart[blockIdx.x] = s;
}

// ====== K_ITER: one full CG iteration ==============================================
// scalars: alpha_{k-1} = rn_{k-1}/pap; rn_k = rn_{k-1} - 2a<r,ap> + a^2<ap,ap>;
//          beta = rn_k/rn_{k-1}
// fields:  x += a*p_old;  r' = r - a*ap_old;  p' = r' + b*p_old;  ap' = A(p')
// dots:    <p',ap'>, <r',ap'>, <ap',ap'>   (enables next iteration's scalars)
__global__ void k_iter(const float* __restrict__ coeff,
                       const float* __restrict__ rIn,  float* __restrict__ rOut,
                       const float* __restrict__ pIn,  float* __restrict__ pOut,
                       const float* __restrict__ apIn, float* __restrict__ apOut,
                       float* __restrict__ x,
                       const double* __restrict__ rrPart,   // first-iter rn source
                       const double* __restrict__ dotsIn, double* __restrict__ dotsOut,
                       const double* __restrict__ rnIn,  double* __restrict__ rnOut,
                       int first) {
    __shared__ double lds[4];
    int t = blockIdx.x * 256 + threadIdx.x;
    int b = t >> 16;
    int rem = t & 65535;
    int i = rem >> 7;
    int j0 = (rem & 127) << 2;
    int idx = (b << 18) + (i << 9) + j0;
    int v = idx >> 2;

    float alphaF = 0.f, betaF = 0.f;
    double rnCur;
    if (first) {
        rnCur = reducePartials256(rrPart + (b << 8), lds);
    } else {
        double rnPrev = rnIn[b];
        double pap  = reducePartials256(dotsIn            + (b << 8), lds);
        double rap  = reducePartials256(dotsIn + NBLK     + (b << 8), lds);
        double apap = reducePartials256(dotsIn + 2*NBLK   + (b << 8), lds);
        alphaF = (float)(rnPrev / fmax(pap, 1e-6));
        double aD = (double)alphaF;
        rnCur  = rnPrev - 2.0 * aD * rap + aD * aD * apap;
        betaF  = (float)(rnCur / fmax(rnPrev, 1e-6));
    }

    double dpap = 0.0, drap = 0.0, dapap = 0.0;
    if (i > 0 && i < S-1) {
        const float4* c4p = (const float4*)coeff;
        float4 cC4 = c4p[v], cN4 = c4p[v+128], cS4 = c4p[v-128];
        const float* cCa=(const float*)&cC4; const float* cNa=(const float*)&cN4;
        const float* cSa=(const float*)&cS4;
        float cW = (j0 > 0)     ? coeff[idx-1] : 0.f;
        float cE = (j0 + 4 < S) ? coeff[idx+4] : 0.f;

        float pnC[4], pnN[4], pnS[4], pnW, pnE, rnC[4];
        if (first) {
            const float4* p4p = (const float4*)pIn;
            float4 pC4 = p4p[v], pN4 = p4p[v+128], pS4 = p4p[v-128];
            const float* pCa=(const float*)&pC4; const float* pNa=(const float*)&pN4;
            const float* pSa=(const float*)&pS4;
            #pragma unroll
            for (int k = 0; k < 4; ++k) {
                pnC[k] = pCa[k]; pnN[k] = pNa[k]; pnS[k] = pSa[k]; rnC[k] = pCa[k];
            }
            pnW = (j0 > 0)     ? pIn[idx-1] : 0.f;
            pnE = (j0 + 4 < S) ? pIn[idx+4] : 0.f;
        } else {
            const float4* r4p = (const float4*)rIn;
            const float4* p4p = (const float4*)pIn;
            const float4* a4p = (const float4*)apIn;
            float4 rC4=r4p[v], rN4=r4p[v+128], rS4=r4p[v-128];
            float4 pC4=p4p[v], pN4=p4p[v+128], pS4=p4p[v-128];
            float4 aC4=a4p[v], aN4=a4p[v+128], aS4=a4p[v-128];
            const float* rCa=(const float*)&rC4; const float* rNa=(const float*)&rN4;
            const float* rSa=(const float*)&rS4;
            const float* pCa=(const float*)&pC4; const float* pNa=(const float*)&pN4;
            const float* pSa=(const float*)&pS4;
            const float* aCa=(const float*)&aC4; const float* aNa=(const float*)&aN4;
            const float* aSa=(const float*)&aS4;
            float rW=0.f,pW=0.f,aW=0.f,rE=0.f,pE=0.f,aE=0.f;
            if (j0 > 0)     { rW = rIn[idx-1]; pW = pIn[idx-1]; aW = apIn[idx-1]; }
            if (j0 + 4 < S) { rE = rIn[idx+4]; pE = pIn[idx+4]; aE = apIn[idx+4]; }

            // x += alpha * p_old (center only)
            float4 x4 = ((const float4*)x)[v];
            x4.x += alphaF * pCa[0]; x4.y += alphaF * pCa[1];
            x4.z += alphaF * pCa[2]; x4.w += alphaF * pCa[3];
            ((float4*)x)[v] = x4;

            #pragma unroll
            for (int k = 0; k < 4; ++k) {
                rnC[k]     = rCa[k] - alphaF * aCa[k];
                pnC[k]     = rnC[k] + betaF * pCa[k];
                float rnNk = rNa[k] - alphaF * aNa[k];
                pnN[k]     = rnNk   + betaF * pNa[k];
                float rnSk = rSa[k] - alphaF * aSa[k];
                pnS[k]     = rnSk   + betaF * pSa[k];
            }
            pnW = (rW - alphaF * aW) + betaF * pW;
            pnE = (rE - alphaF * aE) + betaF * pE;
        }

        float apk[4];
        #pragma unroll
        for (int k = 0; k < 4; ++k) {
            int j = j0 + k;
            if (j > 0 && j < S-1) {
                float cc = cCa[k], cn = cNa[k], cs = cSa[k];
                float ce = (k < 3) ? cCa[k+1] : cE;
                float cw = (k > 0) ? cCa[k-1] : cW;
                float pe = (k < 3) ? pnC[k+1] : pnE;
                float pw = (k > 0) ? pnC[k-1] : pnW;
                float cxN = 2.f * cn * cc / (cn + cc + 1e-6f);
                float cxS = 2.f * cc * cs / (cc + cs + 1e-6f);
                float cyE = 2.f * ce * cc / (ce + cc + 1e-6f);
                float cyW = 2.f * cc * cw / (cc + cw + 1e-6f);
                float qxp = cxN * ((pnN[k] - pnC[k]) * kINVH);
                float qxm = cxS * ((pnC[k] - pnS[k]) * kINVH);
                float qyp = cyE * ((pe - pnC[k]) * kINVH);
                float qym = cyW * ((pnC[k] - pw) * kINVH);
                apk[k] = -((qxp - qxm) * kINVH + (qyp - qym) * kINVH);
            } else {
                apk[k] = pnC[k];               // Dirichlet (value is 0)
            }
            dpap  += (double)pnC[k] * (double)apk[k];
            drap  += (double)rnC[k] * (double)apk[k];
            dapap += (double)apk[k] * (double)apk[k];
        }

        float4 ao; ao.x=apk[0]; ao.y=apk[1]; ao.z=apk[2]; ao.w=apk[3];
        ((float4*)apOut)[v] = ao;
        if (!first) {
            float4 ro; ro.x=rnC[0]; ro.y=rnC[1]; ro.z=rnC[2]; ro.w=rnC[3];
            float4 po; po.x=pnC[0]; po.y=pnC[1]; po.z=pnC[2]; po.w=pnC[3];
            ((float4*)rOut)[v] = ro;
            ((float4*)pOut)[v] = po;
        }
    } else {
        // boundary rows: keep out-buffers zeroed (B-side held setup temps)
        float4 z = make_float4(0.f,0.f,0.f,0.f);
        ((float4*)apOut)[v] = z;
        if (!first) { ((float4*)rOut)[v] = z; ((float4*)pOut)[v] = z; }
    }

    double s1 = blockSum(dpap, lds);
    double s2 = blockSum(drap, lds);
    double s3 = blockSum(dapap, lds);
    if (threadIdx.x == 0) {
        dotsOut[blockIdx.x]          = s1;
        dotsOut[NBLK + blockIdx.x]   = s2;
        dotsOut[2*NBLK + blockIdx.x] = s3;
    }
    if ((blockIdx.x & 255) == 0 && threadIdx.x == 0) rnOut[b] = rnCur;
}

// ====== KF: final alpha; out = zb(u + x + alpha*p_19) ==============================
__global__ void k_fin(const float* __restrict__ u, const float* __restrict__ p,
                      float* __restrict__ out,
                      const double* __restrict__ dotsIn, const double* __restrict__ rnIn) {
    __shared__ double lds[4];
    int t = blockIdx.x * 256 + threadIdx.x;
    int b = t >> 16;
    double pap = reducePartials256(dotsIn + (b << 8), lds);
    float alpha = (float)(rnIn[b] / fmax(pap, 1e-6));
    int rem = t & 65535;
    int i = rem >> 7;
    int j0 = (rem & 127) << 2;
    float4 o = make_float4(0.f,0.f,0.f,0.f);
    if (i > 0 && i < S-1) {
        float4 u4 = ((const float4*)u)[t];
        float4 x4 = ((const float4*)out)[t];
        float4 p4 = ((const float4*)p)[t];
        const float* ua=(const float*)&u4; const float* xa=(const float*)&x4;
        const float* pa=(const float*)&p4; float* oa=(float*)&o;
        #pragma unroll
        for (int k = 0; k < 4; ++k) {
            int j = j0 + k;
            if (j > 0 && j < S-1) oa[k] = ua[k] + xa[k] + alpha * pa[k];
        }
    }
    ((float4*)out)[t] = o;
}

extern "C" void kernel_launch(void* const* d_in, const int* in_sizes, int n_in,
                              void* d_out, int out_size, void* d_ws, size_t ws_size,
                              hipStream_t stream) {
    const float* coeff = (const float*)d_in[0];
    const float* u     = (const float*)d_in[1];
    const float* beta  = (const float*)d_in[2];
    float* x = (float*)d_out;

    float* fb    = (float*)d_ws;
    float* rA    = fb;
    float* rB    = rA    + NTOT;
    float* pA    = rB    + NTOT;
    float* pB    = pA    + NTOT;
    float* apA   = pB    + NTOT;
    float* apB   = apA   + NTOT;
    float* taux  = apB   + NTOT;
    float* tauyP = taux  + NFTOT;
    double* rrPart = (double*)(tauyP + NTOT);
    double* setA   = rrPart + NBLK;        // 3*NBLK doubles
    double* setB   = setA + 3*NBLK;
    double* rnA    = setB + 3*NBLK;        // 8 doubles
    double* rnB    = rnA + Bsz;

    dim3 blk(256);

    // setup: temps lap->rB, rho->pB, sx->apB, sy->apA (all fully rewritten before
    // first read by the loop: apA by it0, rB/pB/apB by it1)
    k_cellfields<<<8192, blk, 0, stream>>>(coeff, u, beta, rB, pB, apB, apA);
    k_faces<<<8192, blk, 0, stream>>>(coeff, u, beta, rB, pB, apB, apA, taux, tauyP);
    k_rhs<<<NBLK, blk, 0, stream>>>(taux, tauyP, rA, pA, x, rrPart);

    // it 0: ap_0 = A(p_0) -> apA; dots_0 -> setA; rn_0 -> rnA
    k_iter<<<NBLK, blk, 0, stream>>>(coeff, rA, rB, pA, pB, apA /*unused in*/, apA,
                                     x, rrPart, setB /*unused*/, setA, rnB /*unused*/, rnA, 1);

    const float *ri=rA, *pi=pA, *ai=apA;
    float *ro=rB, *po=pB, *ao=apB;
    const double *dIn=setA, *rnIn=rnA;
    double *dOut=setB, *rnOut=rnB;
    for (int it = 1; it < CG_ITERS; ++it) {
        k_iter<<<NBLK, blk, 0, stream>>>(coeff, ri, ro, pi, po, ai, ao,
                                         x, rrPart, dIn, dOut, rnIn, rnOut, 0);
        { const float* s=ri; ri=ro; ro=(float*)s; }
        { const float* s=pi; pi=po; po=(float*)s; }
        { const float* s=ai; ai=ao; ao=(float*)s; }
        { const double* s=dIn; dIn=dOut; dOut=(double*)s; }
        { const double* s=rnIn; rnIn=rnOut; rnOut=(double*)s; }
    }

    // final: x += alpha_19*p_19 fused with out = zb(u+x)
    k_fin<<<NBLK, blk, 0, stream>>>(u, pi, x, dIn, rnIn);
}

// Round 5
// 559.840 us; speedup vs baseline: 12.2900x; 1.0653x over previous
//
#include <hip/hip_runtime.h>
#include <math.h>

// Problem constants (match reference)
#define S     512
#define Bsz   8
#define NCELL (S*S)              // 262144 = 2^18
#define NTOT  (Bsz*NCELL)        // 2097152
#define NFACE ((S-1)*S)          // 261632
#define NFTOT (Bsz*NFACE)
#define CG_ITERS 20
#define NBLK  2048               // loop-kernel grid (256 blocks/batch)

__device__ __constant__ float kINVH  = 511.0f;     // 1/h
__device__ __constant__ float kINV2H = 255.5f;
__device__ __constant__ float kH2    = (float)((1.0/511.0)*(1.0/511.0));

// ---------------- geometry (replicates numpy grid_helpers bit-exactly in double) ----
__device__ __forceinline__ void geom(int i, int j, float& rhob, float& bnx, float& bny) {
    double gx = (i == S-1) ? 1.0 : (double)i * (1.0/511.0);
    double gy = (j == S-1) ? 1.0 : (double)j * (1.0/511.0);
    double v0 = gx, v1 = 1.0 - gx, v2 = gy, v3 = 1.0 - gy;
    double m = v0; int am = 0;
    if (v1 < m) { m = v1; am = 1; }   // strict '<' == np.argmin first-min-wins
    if (v2 < m) { m = v2; am = 2; }
    if (v3 < m) { m = v3; am = 3; }
    float d = (float)m;
    rhob = expf(-(d*d) / 0.0225f);
    bnx = (am == 0) ? -1.f : (am == 1) ? 1.f : 0.f;
    bny = (am == 2) ? -1.f : (am == 3) ? 1.f : 0.f;
}

// ================= K1: per-cell fields: lap, rho_int, sx, sy =======================
__global__ void k_cellfields(const float* __restrict__ coeff, const float* __restrict__ u,
                             const float* __restrict__ beta,
                             float* __restrict__ lap, float* __restrict__ rho,
                             float* __restrict__ sx, float* __restrict__ sy) {
    int idx = blockIdx.x * 256 + threadIdx.x;
    int rem = idx & (NCELL - 1);
    int i = rem >> 9, j = rem & (S - 1);
    const float* c  = coeff + (idx - rem);
    const float* uu = u     + (idx - rem);
    float cc = c[rem];

    float lapv = 0.f;
    if (i > 0 && i < S-1 && j > 0 && j < S-1) {
        float uc = uu[rem];
        float un = uu[rem + S], us = uu[rem - S];
        float ue = uu[rem + 1], uw = uu[rem - 1];
        lapv = ((un - uc)*kINVH - (uc - us)*kINVH)*kINVH
             + ((ue - uc)*kINVH - (uc - uw)*kINVH)*kINVH;
    }
    lap[idx] = lapv;

    float glx, gly;
    {
        float lc = logf(fmaxf(cc, 1e-6f));
        if (i == 0)        { glx = (logf(fmaxf(c[rem+S],1e-6f)) - lc) * kINVH; }
        else if (i == S-1) { glx = (lc - logf(fmaxf(c[rem-S],1e-6f))) * kINVH; }
        else { glx = (logf(fmaxf(c[rem+S],1e-6f)) - logf(fmaxf(c[rem-S],1e-6f))) * kINV2H; }
        if (j == 0)        { gly = (logf(fmaxf(c[rem+1],1e-6f)) - lc) * kINVH; }
        else if (j == S-1) { gly = (lc - logf(fmaxf(c[rem-1],1e-6f))) * kINVH; }
        else { gly = (logf(fmaxf(c[rem+1],1e-6f)) - logf(fmaxf(c[rem-1],1e-6f))) * kINV2H; }
    }
    float eta  = sqrtf(glx*glx + gly*gly + 1e-6f);
    float rhov = 1.f / (1.f + expf(-10.f * (eta - 0.5f)));
    float nhx = glx / eta, nhy = gly / eta;

    float4 b4 = ((const float4*)beta)[idx];
    rho[idx] = rhov;
    sx[idx]  = b4.y * nhx - b4.z * nhy;
    sy[idx]  = b4.y * nhy + b4.z * nhx;
}

// ========== K2: fused face taus + harmonic coeffs (cx/cy stored padded) ============
__global__ void k_faces(const float* __restrict__ coeff, const float* __restrict__ u,
                        const float* __restrict__ beta,
                        const float* __restrict__ lap, const float* __restrict__ rho,
                        const float* __restrict__ sx, const float* __restrict__ sy,
                        float* __restrict__ taux, float* __restrict__ tauyP,
                        float* __restrict__ cxP, float* __restrict__ cyP) {
    int idx = blockIdx.x * 256 + threadIdx.x;
    int b = idx >> 18;
    int rem = idx & (NCELL - 1);
    int i = rem >> 9, j = rem & (S - 1);

    float c0 = coeff[idx];
    float u0 = u[idx];
    float lap0 = lap[idx], rho0 = rho[idx];
    float4 b0 = ((const float4*)beta)[idx];
    float rb0, nx0, ny0; geom(i, j, rb0, nx0, ny0);

    if (i < S-1) {
        int c1i = idx + S;
        float c1 = coeff[c1i];
        float cx = 2.f * c1 * c0 / (c1 + c0 + 1e-6f);
        cxP[b * NCELL + i * S + j] = cx;          // padded width-512
        float t = 0.f;
        if (j > 0 && j < S-1) {
            float gux = (u[c1i]   - u0)   * kINVH;
            float lgx = (lap[c1i] - lap0) * kINVH;
            float4 b1 = ((const float4*)beta)[c1i];
            float rb1, nx1, ny1; geom(i+1, j, rb1, nx1, ny1);
            float abb  = 0.5f * (b1.x + b0.x);
            float arho = 0.5f * (rho[c1i] + rho0);
            float asx  = 0.5f * (sx[c1i]  + sx[idx]);
            float arb  = 0.5f * (rb1 + rb0);
            float abx  = 0.5f * (b1.w * nx1 + b0.w * nx0);
            t = abb * kH2 * cx * lgx + arho * asx * cx * gux + arb * abx * cx * gux;
        }
        taux[b * NFACE + i * S + j] = t;
    }
    if (j < S-1) {
        int c1i = idx + 1;
        float c1 = coeff[c1i];
        float cy = 2.f * c1 * c0 / (c1 + c0 + 1e-6f);
        cyP[b * NCELL + i * S + j] = cy;          // padded width-512
        float t = 0.f;
        if (i > 0 && i < S-1) {
            float guy = (u[c1i]   - u0)   * kINVH;
            float lgy = (lap[c1i] - lap0) * kINVH;
            float4 b1 = ((const float4*)beta)[c1i];
            float rb1, nx1, ny1; geom(i, j+1, rb1, nx1, ny1);
            float abb  = 0.5f * (b1.x + b0.x);
            float arho = 0.5f * (rho[c1i] + rho0);
            float asy  = 0.5f * (sy[c1i]  + sy[idx]);
            float arb  = 0.5f * (rb1 + rb0);
            float aby  = 0.5f * (b1.w * ny1 + b0.w * ny0);
            t = abb * kH2 * cy * lgy + arho * asy * cy * guy + arb * aby * cy * guy;
        }
        tauyP[b * NCELL + i * S + j] = t;
    }
}

// ================= K3: rhs = div(tau); r=p=rhs; x=0; rr partials ===================
__global__ void k_rhs(const float* __restrict__ taux, const float* __restrict__ tauyP,
                      float* __restrict__ r, float* __restrict__ p, float* __restrict__ x,
                      double* __restrict__ rrPart) {
    __shared__ double lds[4];
    int t = blockIdx.x * 256 + threadIdx.x;
    int b = t >> 16;
    int rem = t & 65535;
    int i = rem >> 7;
    int j0 = (rem & 127) << 2;

    float4 o = make_float4(0.f, 0.f, 0.f, 0.f);
    float* oa = (float*)&o;
    if (i > 0 && i < S-1) {
        const float* tx  = taux  + b * NFACE;
        const float* typ = tauyP + b * NCELL;
        float4 txC = ((const float4*)tx)[i * 128 + (j0 >> 2)];
        float4 txS = ((const float4*)tx)[(i-1) * 128 + (j0 >> 2)];
        float4 tyC = ((const float4*)typ)[i * 128 + (j0 >> 2)];
        float tyW = (j0 > 0) ? typ[i * S + j0 - 1] : 0.f;
        const float* txCa = (const float*)&txC;
        const float* txSa = (const float*)&txS;
        const float* tyCa = (const float*)&tyC;
        #pragma unroll
        for (int k = 0; k < 4; ++k) {
            int j = j0 + k;
            if (j > 0 && j < S-1) {
                float tyw = (k == 0) ? tyW : tyCa[k-1];
                oa[k] = (txCa[k] - txSa[k]) * kINVH + (tyCa[k] - tyw) * kINVH;
            }
        }
    }
    ((float4*)r)[t] = o;
    ((float4*)p)[t] = o;
    ((float4*)x)[t] = make_float4(0.f, 0.f, 0.f, 0.f);
    double local = (double)oa[0]*oa[0] + (double)oa[1]*oa[1]
                 + (double)oa[2]*oa[2] + (double)oa[3]*oa[3];
    for (int off = 32; off > 0; off >>= 1) local += __shfl_down(local, off, 64);
    int lane = threadIdx.x & 63, wave = threadIdx.x >> 6;
    if (lane == 0) lds[wave] = local;
    __syncthreads();
    if (threadIdx.x == 0) rrPart[blockIdx.x] = lds[0]+lds[1]+lds[2]+lds[3];
}

// ====== K_ITER0: ap0 = A(p0); dots; rn0 from rrPart ================================
__global__ __launch_bounds__(256, 4) void k_iter0(
        const float* __restrict__ cxP, const float* __restrict__ cyP,
        const float* __restrict__ pIn, float* __restrict__ apOut,
        const double* __restrict__ rrPart,
        double* __restrict__ dotsOut, double* __restrict__ rnOut) {
    __shared__ double lds[12];
    int t = blockIdx.x * 256 + threadIdx.x;
    int b = t >> 16;
    int rem = t & 65535;
    int i = rem >> 7;
    int j0 = (rem & 127) << 2;
    int idx = (b << 18) + (i << 9) + j0;
    int v = idx >> 2;
    int lane = threadIdx.x & 63, wave = threadIdx.x >> 6;

    // rn_0 = sum of rhs partials
    {
        double v0 = rrPart[(b << 8) + threadIdx.x];
        #pragma unroll
        for (int off = 32; off > 0; off >>= 1) v0 += __shfl_down(v0, off, 64);
        if (lane == 0) lds[wave] = v0;
    }
    __syncthreads();
    double rnCur = lds[0]+lds[1]+lds[2]+lds[3];

    double dpap = 0.0, dapap = 0.0;
    if (i > 0 && i < S-1) {
        const float4* p4p = (const float4*)pIn;
        float4 pC4 = p4p[v], pN4 = p4p[v+128], pS4 = p4p[v-128];
        float4 cx4 = ((const float4*)cxP)[v];
        float4 cs4 = ((const float4*)cxP)[v-128];
        float4 cy4 = ((const float4*)cyP)[v];
        const float* pCa=(const float*)&pC4; const float* pNa=(const float*)&pN4;
        const float* pSa=(const float*)&pS4;
        const float* cxa=(const float*)&cx4; const float* csa=(const float*)&cs4;
        const float* cya=(const float*)&cy4;
        float cyWs = (j0 > 0)     ? cyP[idx-1] : 0.f;
        float pW   = (j0 > 0)     ? pIn[idx-1] : 0.f;
        float pE   = (j0 + 4 < S) ? pIn[idx+4] : 0.f;

        float apk[4];
        #pragma unroll
        for (int k = 0; k < 4; ++k) {
            int j = j0 + k;
            if (j > 0 && j < S-1) {
                float pe = (k < 3) ? pCa[k+1] : pE;
                float pw = (k > 0) ? pCa[k-1] : pW;
                float cyWk = (k > 0) ? cya[k-1] : cyWs;
                float qxp = cxa[k] * ((pNa[k] - pCa[k]) * kINVH);
                float qxm = csa[k] * ((pCa[k] - pSa[k]) * kINVH);
                float qyp = cya[k] * ((pe - pCa[k]) * kINVH);
                float qym = cyWk   * ((pCa[k] - pw) * kINVH);
                apk[k] = -((qxp - qxm) * kINVH + (qyp - qym) * kINVH);
            } else {
                apk[k] = pCa[k];               // Dirichlet (value is 0)
            }
            dpap  += (double)pCa[k] * (double)apk[k];
            dapap += (double)apk[k] * (double)apk[k];
        }
        float4 ao; ao.x=apk[0]; ao.y=apk[1]; ao.z=apk[2]; ao.w=apk[3];
        ((float4*)apOut)[v] = ao;
    } else {
        ((float4*)apOut)[v] = make_float4(0.f,0.f,0.f,0.f);
    }

    #pragma unroll
    for (int off = 32; off > 0; off >>= 1) {
        dpap  += __shfl_down(dpap,  off, 64);
        dapap += __shfl_down(dapap, off, 64);
    }
    __syncthreads();
    if (lane == 0) { lds[wave] = dpap; lds[4+wave] = dapap; }
    __syncthreads();
    if (threadIdx.x == 0) {
        double s1 = lds[0]+lds[1]+lds[2]+lds[3];
        dotsOut[blockIdx.x]          = s1;
        dotsOut[NBLK + blockIdx.x]   = s1;     // r0 == p0 -> <r,ap> == <p,ap>
        dotsOut[2*NBLK + blockIdx.x] = lds[4]+lds[5]+lds[6]+lds[7];
        if ((blockIdx.x & 255) == 0) rnOut[b] = rnCur;
    }
}

// ====== K_ITER: one full steady CG iteration =======================================
__global__ __launch_bounds__(256, 4) void k_iter(
        const float* __restrict__ cxP, const float* __restrict__ cyP,
        const float* __restrict__ rIn,  float* __restrict__ rOut,
        const float* __restrict__ pIn,  float* __restrict__ pOut,
        const float* __restrict__ apIn, float* __restrict__ apOut,
        float* __restrict__ x,
        const double* __restrict__ dotsIn, double* __restrict__ dotsOut,
        const double* __restrict__ rnIn,  double* __restrict__ rnOut) {
    __shared__ double lds[12];
    int t = blockIdx.x * 256 + threadIdx.x;
    int b = t >> 16;
    int rem = t & 65535;
    int i = rem >> 7;
    int j0 = (rem & 127) << 2;
    int idx = (b << 18) + (i << 9) + j0;
    int v = idx >> 2;
    int lane = threadIdx.x & 63, wave = threadIdx.x >> 6;

    // ---- scalars: fused triple reduce of previous dots ----
    {
        int s = (b << 8) + threadIdx.x;
        double v0 = dotsIn[s];
        double v1 = dotsIn[NBLK + s];
        double v2 = dotsIn[2*NBLK + s];
        #pragma unroll
        for (int off = 32; off > 0; off >>= 1) {
            v0 += __shfl_down(v0, off, 64);
            v1 += __shfl_down(v1, off, 64);
            v2 += __shfl_down(v2, off, 64);
        }
        if (lane == 0) { lds[wave] = v0; lds[4+wave] = v1; lds[8+wave] = v2; }
    }
    __syncthreads();
    double pap  = lds[0]+lds[1]+lds[2]+lds[3];
    double rap  = lds[4]+lds[5]+lds[6]+lds[7];
    double apap = lds[8]+lds[9]+lds[10]+lds[11];
    double rnPrev = rnIn[b];
    float alphaF = (float)(rnPrev / fmax(pap, 1e-6));
    double aD = (double)alphaF;
    double rnCur = rnPrev - 2.0 * aD * rap + aD * aD * apap;
    float betaF = (float)(rnCur / fmax(rnPrev, 1e-6));

    double dpap = 0.0, drap = 0.0, dapap = 0.0;
    if (i > 0 && i < S-1) {
        const float4* r4p = (const float4*)rIn;
        const float4* p4p = (const float4*)pIn;
        const float4* a4p = (const float4*)apIn;
        float4 rC4=r4p[v], rN4=r4p[v+128], rS4=r4p[v-128];
        float4 pC4=p4p[v], pN4=p4p[v+128], pS4=p4p[v-128];
        float4 aC4=a4p[v], aN4=a4p[v+128], aS4=a4p[v-128];
        float4 cx4 = ((const float4*)cxP)[v];
        float4 cs4 = ((const float4*)cxP)[v-128];
        float4 cy4 = ((const float4*)cyP)[v];
        const float* rCa=(const float*)&rC4; const float* rNa=(const float*)&rN4;
        const float* rSa=(const float*)&rS4;
        const float* pCa=(const float*)&pC4; const float* pNa=(const float*)&pN4;
        const float* pSa=(const float*)&pS4;
        const float* aCa=(const float*)&aC4; const float* aNa=(const float*)&aN4;
        const float* aSa=(const float*)&aS4;
        const float* cxa=(const float*)&cx4; const float* csa=(const float*)&cs4;
        const float* cya=(const float*)&cy4;
        float cyWs = (j0 > 0) ? cyP[idx-1] : 0.f;
        float rW=0.f,pW=0.f,aW=0.f,rE=0.f,pE=0.f,aE=0.f;
        if (j0 > 0)     { rW = rIn[idx-1]; pW = pIn[idx-1]; aW = apIn[idx-1]; }
        if (j0 + 4 < S) { rE = rIn[idx+4]; pE = pIn[idx+4]; aE = apIn[idx+4]; }

        // x += alpha * p_old
        float4 x4 = ((const float4*)x)[v];
        x4.x += alphaF * pCa[0]; x4.y += alphaF * pCa[1];
        x4.z += alphaF * pCa[2]; x4.w += alphaF * pCa[3];
        ((float4*)x)[v] = x4;

        float pnC[4], pnN[4], pnS[4], rnC[4];
        #pragma unroll
        for (int k = 0; k < 4; ++k) {
            rnC[k]     = rCa[k] - alphaF * aCa[k];
            pnC[k]     = rnC[k] + betaF * pCa[k];
            float rnNk = rNa[k] - alphaF * aNa[k];
            pnN[k]     = rnNk   + betaF * pNa[k];
            float rnSk = rSa[k] - alphaF * aSa[k];
            pnS[k]     = rnSk   + betaF * pSa[k];
        }
        float pnW = (rW - alphaF * aW) + betaF * pW;
        float pnE = (rE - alphaF * aE) + betaF * pE;

        float apk[4];
        #pragma unroll
        for (int k = 0; k < 4; ++k) {
            int j = j0 + k;
            if (j > 0 && j < S-1) {
                float pe = (k < 3) ? pnC[k+1] : pnE;
                float pw = (k > 0) ? pnC[k-1] : pnW;
                float cyWk = (k > 0) ? cya[k-1] : cyWs;
                float qxp = cxa[k] * ((pnN[k] - pnC[k]) * kINVH);
                float qxm = csa[k] * ((pnC[k] - pnS[k]) * kINVH);
                float qyp = cya[k] * ((pe - pnC[k]) * kINVH);
                float qym = cyWk   * ((pnC[k] - pw) * kINVH);
                apk[k] = -((qxp - qxm) * kINVH + (qyp - qym) * kINVH);
            } else {
                apk[k] = pnC[k];               // Dirichlet (value is 0)
            }
            dpap  += (double)pnC[k] * (double)apk[k];
            drap  += (double)rnC[k] * (double)apk[k];
            dapap += (double)apk[k] * (double)apk[k];
        }

        float4 ao; ao.x=apk[0]; ao.y=apk[1]; ao.z=apk[2]; ao.w=apk[3];
        float4 ro; ro.x=rnC[0]; ro.y=rnC[1]; ro.z=rnC[2]; ro.w=rnC[3];
        float4 po; po.x=pnC[0]; po.y=pnC[1]; po.z=pnC[2]; po.w=pnC[3];
        ((float4*)apOut)[v] = ao;
        ((float4*)rOut)[v] = ro;
        ((float4*)pOut)[v] = po;
    } else {
        float4 z = make_float4(0.f,0.f,0.f,0.f);
        ((float4*)apOut)[v] = z;
        ((float4*)rOut)[v] = z;
        ((float4*)pOut)[v] = z;
    }

    // ---- fused triple block-sum of new dots ----
    #pragma unroll
    for (int off = 32; off > 0; off >>= 1) {
        dpap  += __shfl_down(dpap,  off, 64);
        drap  += __shfl_down(drap,  off, 64);
        dapap += __shfl_down(dapap, off, 64);
    }
    __syncthreads();
    if (lane == 0) { lds[wave] = dpap; lds[4+wave] = drap; lds[8+wave] = dapap; }
    __syncthreads();
    if (threadIdx.x == 0) {
        dotsOut[blockIdx.x]          = lds[0]+lds[1]+lds[2]+lds[3];
        dotsOut[NBLK + blockIdx.x]   = lds[4]+lds[5]+lds[6]+lds[7];
        dotsOut[2*NBLK + blockIdx.x] = lds[8]+lds[9]+lds[10]+lds[11];
        if ((blockIdx.x & 255) == 0) rnOut[b] = rnCur;
    }
}

// ====== KF: final alpha; out = zb(u + x + alpha*p_19) ==============================
__global__ void k_fin(const float* __restrict__ u, const float* __restrict__ p,
                      float* __restrict__ out,
                      const double* __restrict__ dotsIn, const double* __restrict__ rnIn) {
    __shared__ double lds[4];
    int t = blockIdx.x * 256 + threadIdx.x;
    int b = t >> 16;
    int lane = threadIdx.x & 63, wave = threadIdx.x >> 6;
    {
        double v0 = dotsIn[(b << 8) + threadIdx.x];
        #pragma unroll
        for (int off = 32; off > 0; off >>= 1) v0 += __shfl_down(v0, off, 64);
        if (lane == 0) lds[wave] = v0;
    }
    __syncthreads();
    double pap = lds[0]+lds[1]+lds[2]+lds[3];
    float alpha = (float)(rnIn[b] / fmax(pap, 1e-6));
    int rem = t & 65535;
    int i = rem >> 7;
    int j0 = (rem & 127) << 2;
    float4 o = make_float4(0.f,0.f,0.f,0.f);
    if (i > 0 && i < S-1) {
        float4 u4 = ((const float4*)u)[t];
        float4 x4 = ((const float4*)out)[t];
        float4 p4 = ((const float4*)p)[t];
        const float* ua=(const float*)&u4; const float* xa=(const float*)&x4;
        const float* pa=(const float*)&p4; float* oa=(float*)&o;
        #pragma unroll
        for (int k = 0; k < 4; ++k) {
            int j = j0 + k;
            if (j > 0 && j < S-1) oa[k] = ua[k] + xa[k] + alpha * pa[k];
        }
    }
    ((float4*)out)[t] = o;
}

extern "C" void kernel_launch(void* const* d_in, const int* in_sizes, int n_in,
                              void* d_out, int out_size, void* d_ws, size_t ws_size,
                              hipStream_t stream) {
    const float* coeff = (const float*)d_in[0];
    const float* u     = (const float*)d_in[1];
    const float* beta  = (const float*)d_in[2];
    float* x = (float*)d_out;

    // ws: 8 cell-sized float arrays (64 MB) + double partials.
    // Overlays: taux->apB, tauyP->apA (consumed by k_rhs before k_iter writes ap).
    // Setup temps: lap->rB, rho->pB, sx->rA, sy->pA (consumed by k_faces before k_rhs
    // writes rA/pA; rB/pB overwritten at steady iteration 1).
    float* fb  = (float*)d_ws;
    float* rA  = fb;
    float* rB  = rA  + NTOT;
    float* pA  = rB  + NTOT;
    float* pB  = pA  + NTOT;
    float* apA = pB  + NTOT;     // = tauyP during setup
    float* apB = apA + NTOT;     // = taux  during setup
    float* cxP = apB + NTOT;
    float* cyP = cxP + NTOT;
    double* rrPart = (double*)(cyP + NTOT);   // NBLK
    double* setA   = rrPart + NBLK;           // 3*NBLK
    double* setB   = setA + 3*NBLK;
    double* rnA    = setB + 3*NBLK;           // Bsz
    double* rnB    = rnA + Bsz;

    dim3 blk(256);

    k_cellfields<<<8192, blk, 0, stream>>>(coeff, u, beta, rB, pB, rA, pA);
    k_faces<<<8192, blk, 0, stream>>>(coeff, u, beta, rB, pB, rA, pA,
                                      apB /*taux*/, apA /*tauyP*/, cxP, cyP);
    k_rhs<<<NBLK, blk, 0, stream>>>(apB, apA, rA, pA, x, rrPart);
    k_iter0<<<NBLK, blk, 0, stream>>>(cxP, cyP, pA, apA, rrPart, setA, rnA);

    const float *ri=rA, *pi=pA, *ai=apA;
    float *ro=rB, *po=pB, *ao=apB;
    const double *dIn=setA, *rnIn=rnA;
    double *dOut=setB, *rnOut=rnB;
    for (int it = 1; it < CG_ITERS; ++it) {
        k_iter<<<NBLK, blk, 0, stream>>>(cxP, cyP, ri, ro, pi, po, ai, ao,
                                         x, dIn, dOut, rnIn, rnOut);
        { const float* s=ri; ri=ro; ro=(float*)s; }
        { const float* s=pi; pi=po; po=(float*)s; }
        { const float* s=ai; ai=ao; ao=(float*)s; }
        { const double* s=dIn; dIn=dOut; dOut=(double*)s; }
        { const double* s=rnIn; rnIn=rnOut; rnOut=(double*)s; }
    }

    k_fin<<<NBLK, blk, 0, stream>>>(u, pi, x, dIn, rnIn);
}